// Round 5
// baseline (277.554 us; speedup 1.0000x reference)
//
#include <hip/hip_runtime.h>
#include <math.h>

// Sampler: B=256 rows, V=128256 vocab.
// out[b] = (T[b]==0) ? argmax(logits[b,:])
//                    : argmax(logits[b,:]/T[b] - log(-log1p(-noise[b,:])))
// Log-space Gumbel-max (softmax denom + row-max cancel), all in log2 so each
// log is one HW v_log_f32.
//
// R4 post-mortem: compiler collapsed the distance-2 rotation (VGPR=20 proves
// it) -> every wave serializes 2KB round-trips; 2x occupancy changed nothing.
// R5: pin MLP with inline asm. global_load_dwordx4 issued as asm volatile
// (cannot be sunk/merged), s_waitcnt vmcnt(N) with loaded regs threaded
// through "+v" so consumers are dataflow-ordered after the wait. Depth-4
// pair pipeline = 8KB in flight per wave, vmcnt never 0 until the tail.

typedef float f32x4 __attribute__((ext_vector_type(4)));

constexpr int TPB    = 256;
constexpr int CHUNKS = 16;   // blocks per row
constexpr int NIT    = 8;    // ceil(V4c / TPB); V4c = 2004 for V = 128256

#define GLOAD4(dst, ptr) \
    asm volatile("global_load_dwordx4 %0, %1, off" : "=v"(dst) : "v"(ptr))
// wait until <= N vector-mem ops outstanding; thread values through "+v"
#define VWAIT2(N, x, y) \
    asm volatile("s_waitcnt vmcnt(%c2)" : "+v"(x), "+v"(y) : "i"(N))
#define VWAIT1(N, x) \
    asm volatile("s_waitcnt vmcnt(%c1)" : "+v"(x) : "i"(N))

__device__ __forceinline__ void amax_comb(float v, int i, float& bv, int& bi) {
    // np.argmax semantics: strictly greater wins; ties -> lowest index
    if (v > bv || (v == bv && i < bi)) { bv = v; bi = i; }
}

// key = l*c - log2(-log1p(-u)), c = invT/ln2.  Abs err ~1e-6, far below
// top-1/top-2 Gumbel key gaps.  u==0 -> en=0 -> -inf -> key=+inf, matching
// reference probs/0 = +inf (first-index tie-break both sides).
__device__ __forceinline__ float gumbel_key(float l, float u, float c) {
    // u >= 0.125: 1-u exact on the 2^-24 uniform grid, |log2(1-u)| >= 0.19
    const float w   = 1.0f - u;
    const float enw = __log2f(w) * -0.693147180559945f;   // -log(1-u)
    // u < 0.125: en/u = 1 + u/2 + u^2/3 + ... (trunc err < 6e-6 rel)
    float p = 0.16666667f;
    p = fmaf(p, u, 0.2f);
    p = fmaf(p, u, 0.25f);
    p = fmaf(p, u, 0.33333333f);
    p = fmaf(p, u, 0.5f);
    p = fmaf(p, u, 1.0f);
    const float en = (u < 0.125f) ? p * u : enw;
    return fmaf(l, c, -__log2f(en));
}

__device__ __forceinline__ void consume_s(const f32x4 l, const f32x4 u, int f,
                                          int gbase, int V4c, float c,
                                          float& bv, int& bi) {
    if (f < V4c) {
        const int base = (gbase + f) << 2;
        const float k0 = gumbel_key(l.x, u.x, c);
        const float k1 = gumbel_key(l.y, u.y, c);
        const float k2 = gumbel_key(l.z, u.z, c);
        const float k3 = gumbel_key(l.w, u.w, c);
        // per-thread indices ascend -> strict > keeps lowest index
        if (k0 > bv) { bv = k0; bi = base;     }
        if (k1 > bv) { bv = k1; bi = base + 1; }
        if (k2 > bv) { bv = k2; bi = base + 2; }
        if (k3 > bv) { bv = k3; bi = base + 3; }
    }
}

__device__ __forceinline__ void consume_g(const f32x4 l, int f,
                                          int gbase, int V4c,
                                          float& bv, int& bi) {
    if (f < V4c) {
        const int base = (gbase + f) << 2;
        if (l.x > bv) { bv = l.x; bi = base;     }
        if (l.y > bv) { bv = l.y; bi = base + 1; }
        if (l.z > bv) { bv = l.z; bi = base + 2; }
        if (l.w > bv) { bv = l.w; bi = base + 3; }
    }
}

__global__ __launch_bounds__(TPB) void sampler_phase1(
    const float* __restrict__ logits,
    const float* __restrict__ temps,
    const float* __restrict__ noise,
    float* __restrict__ ws_val,
    int* __restrict__ ws_idx, int V)
{
    const int chunk = blockIdx.x & (CHUNKS - 1);
    const int b     = blockIdx.x / CHUNKS;
    const int V4    = V >> 2;            // 32064
    const int V4c   = V4 / CHUNKS;       // 2004 (V divisible by 64)
    const int gbase = chunk * V4c;
    const int last  = V4c - 1;
    const float temp = temps[b];
    const f32x4* __restrict__ lg4 =
        (const f32x4*)(logits + (size_t)b * V) + gbase;
    const f32x4* __restrict__ nz4 =
        (const f32x4*)(noise + (size_t)b * V) + gbase;
    const int t = threadIdx.x;

    float bv = -INFINITY;
    int   bi = 0x7fffffff;

    if (temp == 0.0f) {
        // Greedy: argmax of raw logits only.  Depth-4 single-stream pipeline.
        f32x4 G[4];
        #pragma unroll
        for (int J = 0; J < 4; ++J) {
            const int f = min(t + J * TPB, last);
            GLOAD4(G[J], lg4 + f);
        }
        // steady state: wait vmcnt(3) -> oldest done; consume; refill
        {
            VWAIT1(3, G[0]); consume_g(G[0], t + 0 * TPB, gbase, V4c, bv, bi);
            const int f = min(t + 4 * TPB, last); GLOAD4(G[0], lg4 + f);
        }
        {
            VWAIT1(3, G[1]); consume_g(G[1], t + 1 * TPB, gbase, V4c, bv, bi);
            const int f = min(t + 5 * TPB, last); GLOAD4(G[1], lg4 + f);
        }
        {
            VWAIT1(3, G[2]); consume_g(G[2], t + 2 * TPB, gbase, V4c, bv, bi);
            const int f = min(t + 6 * TPB, last); GLOAD4(G[2], lg4 + f);
        }
        {
            VWAIT1(3, G[3]); consume_g(G[3], t + 3 * TPB, gbase, V4c, bv, bi);
            const int f = min(t + 7 * TPB, last); GLOAD4(G[3], lg4 + f);
        }
        VWAIT1(3, G[0]); consume_g(G[0], t + 4 * TPB, gbase, V4c, bv, bi);
        VWAIT1(2, G[1]); consume_g(G[1], t + 5 * TPB, gbase, V4c, bv, bi);
        VWAIT1(1, G[2]); consume_g(G[2], t + 6 * TPB, gbase, V4c, bv, bi);
        VWAIT1(0, G[3]); consume_g(G[3], t + 7 * TPB, gbase, V4c, bv, bi);
    } else {
        const float c = (1.0f / temp) * 1.4426950408889634f;  // invT / ln2
        // Depth-4 pair pipeline: 8 dwordx4 (8 KB) in flight per wave.
        f32x4 L[4], U[4];
        #pragma unroll
        for (int J = 0; J < 4; ++J) {
            const int f = min(t + J * TPB, last);
            GLOAD4(L[J], lg4 + f);
            GLOAD4(U[J], nz4 + f);
        }
        // steady: wait vmcnt(6) -> oldest pair done; consume; refill
        {
            VWAIT2(6, L[0], U[0]);
            consume_s(L[0], U[0], t + 0 * TPB, gbase, V4c, c, bv, bi);
            const int f = min(t + 4 * TPB, last);
            GLOAD4(L[0], lg4 + f); GLOAD4(U[0], nz4 + f);
        }
        {
            VWAIT2(6, L[1], U[1]);
            consume_s(L[1], U[1], t + 1 * TPB, gbase, V4c, c, bv, bi);
            const int f = min(t + 5 * TPB, last);
            GLOAD4(L[1], lg4 + f); GLOAD4(U[1], nz4 + f);
        }
        {
            VWAIT2(6, L[2], U[2]);
            consume_s(L[2], U[2], t + 2 * TPB, gbase, V4c, c, bv, bi);
            const int f = min(t + 6 * TPB, last);
            GLOAD4(L[2], lg4 + f); GLOAD4(U[2], nz4 + f);
        }
        {
            VWAIT2(6, L[3], U[3]);
            consume_s(L[3], U[3], t + 3 * TPB, gbase, V4c, c, bv, bi);
            const int f = min(t + 7 * TPB, last);
            GLOAD4(L[3], lg4 + f); GLOAD4(U[3], nz4 + f);
        }
        VWAIT2(6, L[0], U[0]);
        consume_s(L[0], U[0], t + 4 * TPB, gbase, V4c, c, bv, bi);
        VWAIT2(4, L[1], U[1]);
        consume_s(L[1], U[1], t + 5 * TPB, gbase, V4c, c, bv, bi);
        VWAIT2(2, L[2], U[2]);
        consume_s(L[2], U[2], t + 6 * TPB, gbase, V4c, c, bv, bi);
        VWAIT2(0, L[3], U[3]);
        consume_s(L[3], U[3], t + 7 * TPB, gbase, V4c, c, bv, bi);
    }
    static_assert(NIT == 8, "pipeline is hand-unrolled for 8 iterations");

    // wave (64-lane) shuffle reduction, lowest-index tie-break
    #pragma unroll
    for (int off = 32; off > 0; off >>= 1) {
        const float ov = __shfl_down(bv, off);
        const int   oi = __shfl_down(bi, off);
        amax_comb(ov, oi, bv, bi);
    }

    __shared__ float s_v[TPB / 64];
    __shared__ int   s_i[TPB / 64];
    const int lane = t & 63;
    const int wave = t >> 6;
    if (lane == 0) { s_v[wave] = bv; s_i[wave] = bi; }
    __syncthreads();
    if (t == 0) {
        #pragma unroll
        for (int w = 1; w < TPB / 64; ++w) amax_comb(s_v[w], s_i[w], bv, bi);
        ws_val[blockIdx.x] = bv;
        ws_idx[blockIdx.x] = bi;
    }
}

__global__ void sampler_phase2(const float* __restrict__ ws_val,
                               const int* __restrict__ ws_idx,
                               int* __restrict__ out, int B)
{
    const int b = blockIdx.x * blockDim.x + threadIdx.x;
    if (b >= B) return;
    float bv = -INFINITY;
    int   bi = 0x7fffffff;
    #pragma unroll
    for (int c = 0; c < CHUNKS; ++c) {
        const float v = ws_val[b * CHUNKS + c];
        const int   i = ws_idx[b * CHUNKS + c];
        // chunk-ascending iteration + strict > keeps lowest index on ties
        if (v > bv || (v == bv && i < bi)) { bv = v; bi = i; }
    }
    out[b] = bi;
}

extern "C" void kernel_launch(void* const* d_in, const int* in_sizes, int n_in,
                              void* d_out, int out_size, void* d_ws, size_t ws_size,
                              hipStream_t stream) {
    const float* logits = (const float*)d_in[0];   // [B, V] fp32
    const float* temps  = (const float*)d_in[1];   // [B]    fp32
    const float* noise  = (const float*)d_in[2];   // [B, V] fp32
    int* out = (int*)d_out;                        // [B]    int32
    const int B = in_sizes[1];
    const int V = in_sizes[0] / B;

    float* ws_val = (float*)d_ws;                       // [B*CHUNKS]
    int*   ws_idx = (int*)d_ws + (size_t)B * CHUNKS;    // [B*CHUNKS]

    sampler_phase1<<<B * CHUNKS, TPB, 0, stream>>>(logits, temps, noise,
                                                   ws_val, ws_idx, V);
    sampler_phase2<<<(B + 255) / 256, 256, 0, stream>>>(ws_val, ws_idx, out, B);
}